// Round 15
// baseline (125.927 us; speedup 1.0000x reference)
//
#include <hip/hip_runtime.h>

#define S_LEN 2048
#define HD 64
#define KVB 64

typedef float f32x4  __attribute__((ext_vector_type(4)));
typedef float f32x16 __attribute__((ext_vector_type(16)));
typedef short bf16x8 __attribute__((ext_vector_type(8)));
typedef int   i32x4  __attribute__((ext_vector_type(4)));

#define SQ_SCALE 0.18033688011112042f   // 0.125 * log2(e)
#define MASK_B  (-1442695.040888963f)   // -1e6 * log2(e); v_exp_f32 -> +0 exactly
#define THR 10.0f

static __device__ __forceinline__ int cvt_pk(float lo, float hi) {
  int r;
  asm("v_cvt_pk_bf16_f32 %0, %1, %2" : "=v"(r) : "v"(lo), "v"(hi));
  return r;
}
static __device__ __forceinline__ float exp2v(float x) {
  float r;
  asm("v_exp_f32 %0, %1" : "=v"(r) : "v"(x));
  return r;
}
// Only safe on DISTINCT values (identical-operand pair can coalesce to
// v_permlane32_swap_b32 vN,vN -> pure swap, wrong; round-9 failure).
static __device__ __forceinline__ void swap32(int &a, int &b) {
  asm("v_permlane32_swap_b32 %0, %1" : "+v"(a), "+v"(b));
}

// ---- kernel 1: per-batch compaction of unmasked key indices (order kept).
// idx values are PRE-SCALED by HD (row offsets), killing per-gather v_mul.
__global__ __launch_bounds__(256)
void build_idx(const int* __restrict__ Mg, int* __restrict__ idxA,
               float* __restrict__ biasA, int* __restrict__ cntA) {
  const int b    = threadIdx.x >> 6;   // one wave per batch
  const int lane = threadIdx.x & 63;
  const int* m   = Mg + (size_t)b * S_LEN;
  int*   idx  = idxA  + (size_t)b * S_LEN;
  float* bias = biasA + (size_t)b * S_LEN;

  int offset = 0;
  for (int kb = 0; kb < S_LEN; kb += 64) {
    int live = (m[kb + lane] != 0);
    unsigned long long bal = __ballot(live);
    unsigned long long lt  = (1ull << lane) - 1ull;
    int pos = offset + (int)__popcll(bal & lt);
    if (live) idx[pos] = (kb + lane) * HD;
    offset += (int)__popcll(bal);
  }
  const int cnt = offset;
  for (int j = lane; j < S_LEN; j += 64) {
    bias[j] = (j < cnt) ? 0.f : MASK_B;
    if (j >= cnt) idx[j] = 0;
  }
  if (lane == 0) cntA[b] = (cnt + 63) & ~63;   // padded to tile multiple
}

// ---- kernel 2: flash attention over gathered (unmasked) keys only.
// Online-max kept (fixed-base refuted on HW in r3/r14); the -mrun subtraction
// is folded into the QK^T accumulator seed (lane-uniform C-seed).
__global__ __launch_bounds__(512, 4)
void attn_fwd(const float* __restrict__ Qg, const float* __restrict__ Kg,
              const float* __restrict__ Vg,
              const int* __restrict__ idxA, const float* __restrict__ biasA,
              const int* __restrict__ cntA, float* __restrict__ Og) {
  // Round-8 proven structure: 2-deep, one barrier per tile.
  // K tile [64 keys][72 d] bf16; V^T tile [64 d][72 keys] bf16 (conflict-free)
  __shared__ __align__(16) short Klds[2][64 * 72];
  __shared__ __align__(16) short Vtld[2][64 * 72];
  __shared__ __align__(16) float MB[2][64];

  const int t    = threadIdx.x;
  const int lane = t & 63;
  const int wid  = t >> 6;      // 0..7
  const int c    = lane & 31;   // q column (and d-row for V^T A-frag)
  const int hi   = lane >> 5;   // lane half

  // XCD-aware swizzle (bijective: 512 = 8 XCDs x 64)
  const int bid  = (int)blockIdx.x;
  const int swz  = (bid & 7) * 64 + (bid >> 3);
  const int bh   = swz >> 3;                // 0..63
  const int qblk = (swz & 7) * 256;         // 256 q rows per block
  const int b    = bh >> 4;                 // batch (H=16)
  const size_t base = (size_t)bh * S_LEN * HD;
  const int qbase = qblk + wid * 32;        // this wave's 32 q rows

  const int*   idx  = idxA  + (size_t)b * S_LEN;
  const float* bias = biasA + (size_t)b * S_LEN;
  const int NTd = cntA[b] >> 6;             // live tiles

  // ---- Q fragment (B-operand of QK^T): lane holds Q[qbase+c][16s+8hi .. +7]
  bf16x8 qf[4];
#pragma unroll
  for (int s = 0; s < 4; ++s) {
    const float* qp = Qg + base + (size_t)(qbase + c) * HD + 16*s + 8*hi;
    float4 x0 = *(const float4*)qp;
    float4 x1 = *(const float4*)(qp + 4);
    i32x4 w;
    w[0] = cvt_pk(x0.x*SQ_SCALE, x0.y*SQ_SCALE);
    w[1] = cvt_pk(x0.z*SQ_SCALE, x0.w*SQ_SCALE);
    w[2] = cvt_pk(x1.x*SQ_SCALE, x1.y*SQ_SCALE);
    w[3] = cvt_pk(x1.z*SQ_SCALE, x1.w*SQ_SCALE);
    qf[s] = __builtin_bit_cast(bf16x8, w);
  }

  // ---- staging roles (512 threads stage one 64-key K tile + V tile)
  const int kkey = t >> 3;                 // slot within tile
  const int kdg  = (t & 7) ^ (kkey & 7);   // XOR'd d-block (bank spread)
  const int vd   = t & 63;                 // V: column d
  const int vkg  = t >> 6;                 // V: 8-key group

  float kr[8], vr[8]; float mbias = 0.f;

  auto LOADT = [&](int it) {   // gather tile it's live keys (idx pre-scaled)
    const int tb = it * KVB;
    const int koff = idx[tb + kkey];
    const float* kp = Kg + base + koff + 8*kdg;
    *(float4*)&kr[0] = *(const float4*)kp;
    *(float4*)&kr[4] = *(const float4*)(kp + 4);
    i32x4 ra = *(const i32x4*)&idx[tb + 8*vkg];
    i32x4 rb = *(const i32x4*)&idx[tb + 8*vkg + 4];
#pragma unroll
    for (int j = 0; j < 4; ++j) vr[j]   = Vg[base + ra[j] + vd];
#pragma unroll
    for (int j = 0; j < 4; ++j) vr[4+j] = Vg[base + rb[j] + vd];
    // Bias is only ever READ on the last tile; skip its staging elsewhere.
    if (t < 64 && it == NTd - 1) mbias = bias[tb + t];
  };
  auto STORET = [&](int bf) {
    i32x4 kw;
    kw[0] = cvt_pk(kr[0], kr[1]); kw[1] = cvt_pk(kr[2], kr[3]);
    kw[2] = cvt_pk(kr[4], kr[5]); kw[3] = cvt_pk(kr[6], kr[7]);
    *(i32x4*)&Klds[bf][kkey*72 + 8*kdg] = kw;
    i32x4 vw;
    vw[0] = cvt_pk(vr[0], vr[1]); vw[1] = cvt_pk(vr[2], vr[3]);
    vw[2] = cvt_pk(vr[4], vr[5]); vw[3] = cvt_pk(vr[6], vr[7]);
    *(i32x4*)&Vtld[bf][vd*72 + 8*vkg] = vw;
    if (t < 64) MB[bf][t] = mbias;   // stale except for the last tile's chain
  };

  f32x16 acc0 = {};  // O^T rows d=0..31
  f32x16 acc1 = {};  // O^T rows d=32..63
  float mrun = 0.f;  // running max, init 0 (first defer-check rescales as needed)
  float lrun = 0.f;  // per-lane partial row-sum; merged across hi at epilogue
                     // (rescale factor is hi-uniform: tmax is shfl-merged)

  // Round-13 group body with -mrun folded into the MFMA C-seed.
  auto GROUP = [&](int cur, int grp, bool lastTile) {
    const int kc = 32 * grp;
    // ---- S^T = K · Q^T - mrun  (lane-uniform C-seed; rows = keys kc..kc+31)
    const float negm = -mrun;
    f32x16 S;
#pragma unroll
    for (int r = 0; r < 16; ++r) S[r] = negm;
    __builtin_amdgcn_s_setprio(1);
#pragma unroll
    for (int s = 0; s < 4; ++s) {
      bf16x8 kf = *(const bf16x8*)&Klds[cur][(kc + c)*72 + 16*s + 8*hi];
      S = __builtin_amdgcn_mfma_f32_32x32x16_bf16(kf, qf[s], S, 0, 0, 0);
    }
    __builtin_amdgcn_s_setprio(0);

    // sb[r]: (logit2 - mrun) for key kc + (r&3)+8*(r>>2)+4*hi, q=c
    float sb[16];
    if (lastTile) {
      f32x4 b4[4];
#pragma unroll
      for (int m = 0; m < 4; ++m)
        b4[m] = *(const f32x4*)&MB[cur][kc + 8*m + 4*hi];
#pragma unroll
      for (int r = 0; r < 16; ++r)
        sb[r] = S[r] + b4[r >> 2][r & 3];
    } else {
#pragma unroll
      for (int r = 0; r < 16; ++r) sb[r] = S[r];
    }

    // shifted row max over this group's 32 keys
    float mx[8];
#pragma unroll
    for (int r = 0; r < 8; ++r) mx[r] = fmaxf(sb[r], sb[r+8]);
#pragma unroll
    for (int r = 0; r < 4; ++r) mx[r] = fmaxf(mx[r], mx[r+4]);
    float tmax = fmaxf(fmaxf(mx[0], mx[1]), fmaxf(mx[2], mx[3]));
    tmax = fmaxf(tmax, __shfl_xor(tmax, 32, 64));

    // defer-max: rescale only when the (shifted) max exceeds THR
    if (!__all(tmax <= THR)) {
      float delta = fmaxf(tmax, 0.f);     // mrun never decreases
      float al = exp2v(-delta);
      acc0 *= al; acc1 *= al;
      lrun *= al; mrun += delta;
#pragma unroll
      for (int r = 0; r < 16; ++r) sb[r] -= delta;
    }

    // p = exp2(sb) — subtraction already folded into the seed
    float p0[8], p1[8];
#pragma unroll
    for (int r = 0; r < 8; ++r) p0[r] = exp2v(sb[r]);
#pragma unroll
    for (int r = 0; r < 8; ++r) p1[r] = exp2v(sb[8 + r]);

    // pack P to bf16 B-fragments (distinct-value permlane recipe)
    int w0 = cvt_pk(p0[0], p0[1]), w1 = cvt_pk(p0[2], p0[3]);
    int w2 = cvt_pk(p0[4], p0[5]), w3 = cvt_pk(p0[6], p0[7]);
    swap32(w0, w2); swap32(w1, w3);
    i32x4 pq0 = {w0, w1, w2, w3};
    bf16x8 pb0 = __builtin_bit_cast(bf16x8, pq0);   // keys kc..kc+15
    int w4 = cvt_pk(p1[0], p1[1]), w5 = cvt_pk(p1[2], p1[3]);
    int w6 = cvt_pk(p1[4], p1[5]), w7 = cvt_pk(p1[6], p1[7]);
    swap32(w4, w6); swap32(w5, w7);
    i32x4 pq1 = {w4, w5, w6, w7};
    bf16x8 pb1 = __builtin_bit_cast(bf16x8, pq1);   // keys kc+16..kc+31

    // V fragments just-in-time (16 regs only)
    bf16x8 vA0 = *(const bf16x8*)&Vtld[cur][(c     )*72 + kc      + 8*hi];
    bf16x8 vA1 = *(const bf16x8*)&Vtld[cur][(c     )*72 + kc + 16 + 8*hi];
    bf16x8 vB0 = *(const bf16x8*)&Vtld[cur][(c + 32)*72 + kc      + 8*hi];
    bf16x8 vB1 = *(const bf16x8*)&Vtld[cur][(c + 32)*72 + kc + 16 + 8*hi];

    // ---- O^T += V^T · P^T
    __builtin_amdgcn_s_setprio(1);
    acc0 = __builtin_amdgcn_mfma_f32_32x32x16_bf16(vA0, pb0, acc0, 0, 0, 0);
    acc1 = __builtin_amdgcn_mfma_f32_32x32x16_bf16(vB0, pb0, acc1, 0, 0, 0);
    acc0 = __builtin_amdgcn_mfma_f32_32x32x16_bf16(vA1, pb1, acc0, 0, 0, 0);
    acc1 = __builtin_amdgcn_mfma_f32_32x32x16_bf16(vB1, pb1, acc1, 0, 0, 0);
    __builtin_amdgcn_s_setprio(0);

    // per-lane partial row-sum (no per-tile shfl)
    float s0 = ((p0[0]+p0[1]) + (p0[2]+p0[3])) + ((p0[4]+p0[5]) + (p0[6]+p0[7]));
    float s1 = ((p1[0]+p1[1]) + (p1[2]+p1[3])) + ((p1[4]+p1[5]) + (p1[6]+p1[7]));
    lrun += s0 + s1;
  };

  // ---- prologue (round-8 proven loop: 2-deep, barrier per tile)
  LOADT(0); STORET(0);
  if (NTd > 1) LOADT(1);
  __syncthreads();

  for (int it = 0; it < NTd; ++it) {
    if (it + 1 < NTd) STORET((it + 1) & 1);
    if (it + 2 < NTd) LOADT(it + 2);
    const int cur = it & 1;
    const bool lt = (it == NTd - 1);
    GROUP(cur, 0, lt);
    GROUP(cur, 1, lt);
    __syncthreads();
  }

  // ---- epilogue: merge partial l across hi halves (shfl); store fp32
  float lfull = lrun + __shfl_xor(lrun, 32, 64);
  const float linv = 1.0f / lfull;
  float* op = Og + base + (size_t)(qbase + c) * HD + 4*hi;
#pragma unroll
  for (int m = 0; m < 4; ++m) {
    f32x4 o0, o1;
#pragma unroll
    for (int j = 0; j < 4; ++j) {
      o0[j] = acc0[4*m + j] * linv;
      o1[j] = acc1[4*m + j] * linv;
    }
    *(f32x4*)(op + 8*m)      = o0;   // d = 8m+4hi .. +3
    *(f32x4*)(op + 32 + 8*m) = o1;   // d = 32+8m+4hi .. +3
  }
}

extern "C" void kernel_launch(void* const* d_in, const int* in_sizes, int n_in,
                              void* d_out, int out_size, void* d_ws, size_t ws_size,
                              hipStream_t stream) {
    const float* Q = (const float*)d_in[0];
    const float* K = (const float*)d_in[1];
    const float* V = (const float*)d_in[2];
    const int*   M = (const int*)d_in[3];
    float* O = (float*)d_out;

    // ws layout: idx[4][2048] int | bias[4][2048] f32 | cnt[4] int
    char* ws = (char*)d_ws;
    int*   idxA  = (int*)ws;
    float* biasA = (float*)(ws + 4 * S_LEN * sizeof(int));
    int*   cntA  = (int*)(ws + 8 * S_LEN * sizeof(int));

    hipLaunchKernelGGL(build_idx, dim3(1), dim3(256), 0, stream, M, idxA, biasA, cntA);
    hipLaunchKernelGGL(attn_fwd, dim3(512), dim3(512), 0, stream,
                       Q, K, V, idxA, biasA, cntA, O);
}

// Round 16
// 77.753 us; speedup vs baseline: 1.6196x; 1.6196x over previous
//
#include <hip/hip_runtime.h>

#define S_LEN 2048
#define HD 64
#define KVB 64

typedef float f32x4  __attribute__((ext_vector_type(4)));
typedef float f32x16 __attribute__((ext_vector_type(16)));
typedef short bf16x8 __attribute__((ext_vector_type(8)));
typedef int   i32x4  __attribute__((ext_vector_type(4)));

#define SQ_SCALE 0.18033688011112042f   // 0.125 * log2(e)
#define MASK_B  (-1442695.040888963f)   // -1e6 * log2(e)
#define THR 10.0f

static __device__ __forceinline__ int cvt_pk(float lo, float hi) {
  int r;
  asm("v_cvt_pk_bf16_f32 %0, %1, %2" : "=v"(r) : "v"(lo), "v"(hi));
  return r;
}
static __device__ __forceinline__ float exp2v(float x) {
  float r;
  asm("v_exp_f32 %0, %1" : "=v"(r) : "v"(x));
  return r;
}
// Only safe on DISTINCT values (identical-operand pair can coalesce to
// v_permlane32_swap_b32 vN,vN -> pure swap, wrong; round-9 failure).
static __device__ __forceinline__ void swap32(int &a, int &b) {
  asm("v_permlane32_swap_b32 %0, %1" : "+v"(a), "+v"(b));
}

// ---- kernel 1: per-batch compaction of unmasked key indices (order kept).
// idx values are PRE-SCALED by HD (row offsets), killing per-gather v_mul.
__global__ __launch_bounds__(256)
void build_idx(const int* __restrict__ Mg, int* __restrict__ idxA,
               float* __restrict__ biasA, int* __restrict__ cntA) {
  const int b    = threadIdx.x >> 6;   // one wave per batch
  const int lane = threadIdx.x & 63;
  const int* m   = Mg + (size_t)b * S_LEN;
  int*   idx  = idxA  + (size_t)b * S_LEN;
  float* bias = biasA + (size_t)b * S_LEN;

  int offset = 0;
  for (int kb = 0; kb < S_LEN; kb += 64) {
    int live = (m[kb + lane] != 0);
    unsigned long long bal = __ballot(live);
    unsigned long long lt  = (1ull << lane) - 1ull;
    int pos = offset + (int)__popcll(bal & lt);
    if (live) idx[pos] = (kb + lane) * HD;
    offset += (int)__popcll(bal);
  }
  const int cnt = offset;
  for (int j = lane; j < S_LEN; j += 64) {
    bias[j] = (j < cnt) ? 0.f : MASK_B;
    if (j >= cnt) idx[j] = 0;
  }
  if (lane == 0) cntA[b] = (cnt + 63) & ~63;   // padded to tile multiple
}

// ---- kernel 2: flash attention over gathered (unmasked) keys only.
__global__ __launch_bounds__(512, 4)
void attn_fwd(const float* __restrict__ Qg, const float* __restrict__ Kg,
              const float* __restrict__ Vg,
              const int* __restrict__ idxA, const float* __restrict__ biasA,
              const int* __restrict__ cntA, float* __restrict__ Og) {
  // Round-8 proven structure: 2-deep, one barrier per tile.
  // K tile [64 keys][72 d] bf16; V^T tile [64 d][72 keys] bf16 (conflict-free)
  __shared__ __align__(16) short Klds[2][64 * 72];
  __shared__ __align__(16) short Vtld[2][64 * 72];
  __shared__ __align__(16) float MB[2][64];

  const int t    = threadIdx.x;
  const int lane = t & 63;
  const int wid  = t >> 6;      // 0..7
  const int c    = lane & 31;   // q column (and d-row for V^T A-frag)
  const int hi   = lane >> 5;   // lane half

  // XCD-aware swizzle (bijective: 512 = 8 XCDs x 64)
  const int bid  = (int)blockIdx.x;
  const int swz  = (bid & 7) * 64 + (bid >> 3);
  const int bh   = swz >> 3;                // 0..63
  const int qblk = (swz & 7) * 256;         // 256 q rows per block
  const int b    = bh >> 4;                 // batch (H=16)
  const size_t base = (size_t)bh * S_LEN * HD;
  const int qbase = qblk + wid * 32;        // this wave's 32 q rows

  const int*   idx  = idxA  + (size_t)b * S_LEN;
  const float* bias = biasA + (size_t)b * S_LEN;
  const int NTd = cntA[b] >> 6;             // live tiles

  // ---- Q fragment (B-operand of QK^T): lane holds Q[qbase+c][16s+8hi .. +7]
  bf16x8 qf[4];
#pragma unroll
  for (int s = 0; s < 4; ++s) {
    const float* qp = Qg + base + (size_t)(qbase + c) * HD + 16*s + 8*hi;
    float4 x0 = *(const float4*)qp;
    float4 x1 = *(const float4*)(qp + 4);
    i32x4 w;
    w[0] = cvt_pk(x0.x*SQ_SCALE, x0.y*SQ_SCALE);
    w[1] = cvt_pk(x0.z*SQ_SCALE, x0.w*SQ_SCALE);
    w[2] = cvt_pk(x1.x*SQ_SCALE, x1.y*SQ_SCALE);
    w[3] = cvt_pk(x1.z*SQ_SCALE, x1.w*SQ_SCALE);
    qf[s] = __builtin_bit_cast(bf16x8, w);
  }

  // ---- staging roles (512 threads stage one 64-key K tile + V tile)
  const int kkey = t >> 3;                 // slot within tile
  const int kdg  = (t & 7) ^ (kkey & 7);   // XOR'd d-block (bank spread)
  const int vd   = t & 63;                 // V: column d
  const int vkg  = t >> 6;                 // V: 8-key group

  float kr[8], vr[8]; float mbias = 0.f;

  auto LOADT = [&](int it) {   // gather tile it's live keys (idx pre-scaled)
    const int tb = it * KVB;
    const int koff = idx[tb + kkey];
    const float* kp = Kg + base + koff + 8*kdg;
    *(float4*)&kr[0] = *(const float4*)kp;
    *(float4*)&kr[4] = *(const float4*)(kp + 4);
    i32x4 ra = *(const i32x4*)&idx[tb + 8*vkg];
    i32x4 rb = *(const i32x4*)&idx[tb + 8*vkg + 4];
#pragma unroll
    for (int j = 0; j < 4; ++j) vr[j]   = Vg[base + ra[j] + vd];
#pragma unroll
    for (int j = 0; j < 4; ++j) vr[4+j] = Vg[base + rb[j] + vd];
    // Bias is only ever READ on the last tile; skip its staging elsewhere.
    if (t < 64 && it == NTd - 1) mbias = bias[tb + t];
  };
  auto STORET = [&](int bf) {
    i32x4 kw;
    kw[0] = cvt_pk(kr[0], kr[1]); kw[1] = cvt_pk(kr[2], kr[3]);
    kw[2] = cvt_pk(kr[4], kr[5]); kw[3] = cvt_pk(kr[6], kr[7]);
    *(i32x4*)&Klds[bf][kkey*72 + 8*kdg] = kw;
    i32x4 vw;
    vw[0] = cvt_pk(vr[0], vr[1]); vw[1] = cvt_pk(vr[2], vr[3]);
    vw[2] = cvt_pk(vr[4], vr[5]); vw[3] = cvt_pk(vr[6], vr[7]);
    *(i32x4*)&Vtld[bf][vd*72 + 8*vkg] = vw;
    if (t < 64) MB[bf][t] = mbias;   // stale except for the last tile's chain
  };

  f32x16 acc0 = {};  // O^T rows d=0..31
  f32x16 acc1 = {};  // O^T rows d=32..63
  float mrun = -1e30f;
  float lrun = 0.f;  // per-lane partial row-sum; merged across hi at epilogue
                     // (rescale factor is hi-uniform: tmax is shfl-merged)

  // Round-8 proven 32-key group body; state scoped (no-spill peak).
  auto GROUP = [&](int cur, int grp, bool lastTile) {
    const int kc = 32 * grp;
    // ---- S^T = K · Q^T  (rows = keys kc..kc+31, cols = q)
    f32x16 S = {};
    __builtin_amdgcn_s_setprio(1);
#pragma unroll
    for (int s = 0; s < 4; ++s) {
      bf16x8 kf = *(const bf16x8*)&Klds[cur][(kc + c)*72 + 16*s + 8*hi];
      S = __builtin_amdgcn_mfma_f32_32x32x16_bf16(kf, qf[s], S, 0, 0, 0);
    }
    __builtin_amdgcn_s_setprio(0);

    // sb[r]: logit2 for key kc + (r&3)+8*(r>>2)+4*hi, q=c
    float sb[16];
    if (lastTile) {
      f32x4 b4[4];
#pragma unroll
      for (int m = 0; m < 4; ++m)
        b4[m] = *(const f32x4*)&MB[cur][kc + 8*m + 4*hi];
#pragma unroll
      for (int r = 0; r < 16; ++r)
        sb[r] = S[r] + b4[r >> 2][r & 3];
    } else {
#pragma unroll
      for (int r = 0; r < 16; ++r) sb[r] = S[r];
    }

    // row max over this group's 32 keys
    float mx[8];
#pragma unroll
    for (int r = 0; r < 8; ++r) mx[r] = fmaxf(sb[r], sb[r+8]);
#pragma unroll
    for (int r = 0; r < 4; ++r) mx[r] = fmaxf(mx[r], mx[r+4]);
    float tmax = fmaxf(fmaxf(mx[0], mx[1]), fmaxf(mx[2], mx[3]));
    tmax = fmaxf(tmax, __shfl_xor(tmax, 32, 64));

    // defer-max: rescale only when the running max grows by > THR
    if (!__all(tmax <= mrun + THR)) {
      float mnew = fmaxf(mrun, tmax);
      float al = exp2v(mrun - mnew);
      acc0 *= al; acc1 *= al;
      lrun *= al; mrun = mnew;
    }

    // p = exp2(logit2 - m)
    float p0[8], p1[8];
#pragma unroll
    for (int r = 0; r < 8; ++r) p0[r] = exp2v(sb[r] - mrun);
#pragma unroll
    for (int r = 0; r < 8; ++r) p1[r] = exp2v(sb[8 + r] - mrun);

    // pack P to bf16 B-fragments (distinct-value permlane recipe)
    int w0 = cvt_pk(p0[0], p0[1]), w1 = cvt_pk(p0[2], p0[3]);
    int w2 = cvt_pk(p0[4], p0[5]), w3 = cvt_pk(p0[6], p0[7]);
    swap32(w0, w2); swap32(w1, w3);
    i32x4 pq0 = {w0, w1, w2, w3};
    bf16x8 pb0 = __builtin_bit_cast(bf16x8, pq0);   // keys kc..kc+15
    int w4 = cvt_pk(p1[0], p1[1]), w5 = cvt_pk(p1[2], p1[3]);
    int w6 = cvt_pk(p1[4], p1[5]), w7 = cvt_pk(p1[6], p1[7]);
    swap32(w4, w6); swap32(w5, w7);
    i32x4 pq1 = {w4, w5, w6, w7};
    bf16x8 pb1 = __builtin_bit_cast(bf16x8, pq1);   // keys kc+16..kc+31

    // V fragments just-in-time (16 regs only)
    bf16x8 vA0 = *(const bf16x8*)&Vtld[cur][(c     )*72 + kc      + 8*hi];
    bf16x8 vA1 = *(const bf16x8*)&Vtld[cur][(c     )*72 + kc + 16 + 8*hi];
    bf16x8 vB0 = *(const bf16x8*)&Vtld[cur][(c + 32)*72 + kc      + 8*hi];
    bf16x8 vB1 = *(const bf16x8*)&Vtld[cur][(c + 32)*72 + kc + 16 + 8*hi];

    // ---- O^T += V^T · P^T
    __builtin_amdgcn_s_setprio(1);
    acc0 = __builtin_amdgcn_mfma_f32_32x32x16_bf16(vA0, pb0, acc0, 0, 0, 0);
    acc1 = __builtin_amdgcn_mfma_f32_32x32x16_bf16(vB0, pb0, acc1, 0, 0, 0);
    acc0 = __builtin_amdgcn_mfma_f32_32x32x16_bf16(vA1, pb1, acc0, 0, 0, 0);
    acc1 = __builtin_amdgcn_mfma_f32_32x32x16_bf16(vB1, pb1, acc1, 0, 0, 0);
    __builtin_amdgcn_s_setprio(0);

    // per-lane partial row-sum (no per-tile shfl)
    float s0 = ((p0[0]+p0[1]) + (p0[2]+p0[3])) + ((p0[4]+p0[5]) + (p0[6]+p0[7]));
    float s1 = ((p1[0]+p1[1]) + (p1[2]+p1[3])) + ((p1[4]+p1[5]) + (p1[6]+p1[7]));
    lrun += s0 + s1;
  };

  // ---- prologue (round-8 proven loop: 2-deep, barrier per tile)
  LOADT(0); STORET(0);
  if (NTd > 1) LOADT(1);
  __syncthreads();

  for (int it = 0; it < NTd; ++it) {
    if (it + 1 < NTd) STORET((it + 1) & 1);
    if (it + 2 < NTd) LOADT(it + 2);
    const int cur = it & 1;
    const bool lt = (it == NTd - 1);
    GROUP(cur, 0, lt);
    GROUP(cur, 1, lt);
    __syncthreads();
  }

  // ---- epilogue: merge partial l across hi halves (shfl); store fp32
  float lfull = lrun + __shfl_xor(lrun, 32, 64);
  const float linv = 1.0f / lfull;
  float* op = Og + base + (size_t)(qbase + c) * HD + 4*hi;
#pragma unroll
  for (int m = 0; m < 4; ++m) {
    f32x4 o0, o1;
#pragma unroll
    for (int j = 0; j < 4; ++j) {
      o0[j] = acc0[4*m + j] * linv;
      o1[j] = acc1[4*m + j] * linv;
    }
    *(f32x4*)(op + 8*m)      = o0;   // d = 8m+4hi .. +3
    *(f32x4*)(op + 32 + 8*m) = o1;   // d = 32+8m+4hi .. +3
  }
}

extern "C" void kernel_launch(void* const* d_in, const int* in_sizes, int n_in,
                              void* d_out, int out_size, void* d_ws, size_t ws_size,
                              hipStream_t stream) {
    const float* Q = (const float*)d_in[0];
    const float* K = (const float*)d_in[1];
    const float* V = (const float*)d_in[2];
    const int*   M = (const int*)d_in[3];
    float* O = (float*)d_out;

    // ws layout: idx[4][2048] int | bias[4][2048] f32 | cnt[4] int
    char* ws = (char*)d_ws;
    int*   idxA  = (int*)ws;
    float* biasA = (float*)(ws + 4 * S_LEN * sizeof(int));
    int*   cntA  = (int*)(ws + 8 * S_LEN * sizeof(int));

    hipLaunchKernelGGL(build_idx, dim3(1), dim3(256), 0, stream, M, idxA, biasA, cntA);
    hipLaunchKernelGGL(attn_fwd, dim3(512), dim3(512), 0, stream,
                       Q, K, V, idxA, biasA, cntA, O);
}